// Round 1
// 3329.672 us; speedup vs baseline: 1.4545x; 1.4545x over previous
//
#include <hip/hip_runtime.h>
#include <stdint.h>

#define NB 256
#define NBATCH 128
#define HID 64
#define MAXEV 5
#define MAXSTEPS 256
#define NT 43          /* 43*6 = 258 >= 256 */
#define NTILES 946     /* 43*44/2 */
#define W2S 65         /* padded LDS stride for W2 rows */
#define CAND_MAX 6144
#define CMARGIN 1.5f   /* total gap-shrink budget of a candidate list */

__device__ __forceinline__ float bf2f(unsigned short u) {
    return __uint_as_float(((unsigned)u) << 16);
}
__device__ __forceinline__ unsigned short f2bf(float f) {
    unsigned u = __float_as_uint(f);
    u += 0x7FFFu + ((u >> 16) & 1u);
    return (unsigned short)(u >> 16);
}
__device__ __forceinline__ float rdin(const void* p, int idx, int bf) {
    return bf ? bf2f(((const unsigned short*)p)[idx]) : ((const float*)p)[idx];
}
__device__ __forceinline__ float silu_f(float x) {
    float s = __fdiv_rn(1.0f, __fadd_rn(1.0f, expf(-x)));
    return __fmul_rn(x, s);
}
__device__ __forceinline__ void lds_fence() {   // in-wave LDS round-trip ordering
    __builtin_amdgcn_wave_barrier();
    __threadfence_block();
    __builtin_amdgcn_wave_barrier();
}
__device__ __forceinline__ unsigned long long shfl_down_u64(unsigned long long v, int off) {
    unsigned lo = (unsigned)v, hi = (unsigned)(v >> 32);
    lo = __shfl_down(lo, off);
    hi = __shfl_down(hi, off);
    return (((unsigned long long)hi) << 32) | lo;
}

__device__ void load_weights(float* w1, float* b1s, float* w2, float* b2s, float* w3, float* b3s,
                             const void* W1, const void* B1, const void* W2, const void* B2,
                             const void* W3, const void* B3, int bf, int tid, int nthr) {
    for (int k = tid; k < HID * 2; k += nthr) w1[k] = rdin(W1, k, bf);
    for (int k = tid; k < HID; k += nthr) {
        b1s[k] = rdin(B1, k, bf);
        b2s[k] = rdin(B2, k, bf);
        w3[k]  = rdin(W3, k, bf);
    }
    for (int k = tid; k < HID * HID; k += nthr) {
        int m = k >> 6, c = k & 63;
        w2[m * W2S + c] = rdin(W2, k, bf);
    }
    if (tid == 0) b3s[0] = rdin(B3, 0, bf);
}

// exact-reference pair evaluation; updates min-key kP
__device__ __forceinline__ void pair_min(const float4* ps, int i, int j, unsigned long long& kP) {
    float4 A = ps[i], B = ps[j];
    float dx = __fsub_rn(B.x, A.x), dy = __fsub_rn(B.y, A.y);
    float d2 = __fadd_rn(__fmul_rn(dx, dx), __fmul_rn(dy, dy));
    float p1 = __fmul_rn(__fsub_rn(B.z, A.z), dx);
    float p2 = __fmul_rn(__fsub_rn(B.w, A.w), dy);
    float dot = __fadd_rn(p1, p2);
    float mag = __fadd_rn(fabsf(p1), fabsf(p2));
    bool appr;
    if (fabsf(dot) < __fmul_rn(1e-5f, mag)) {
        float dist = __fsqrt_rn(d2);
        float den = __fadd_rn(dist, 1e-8f);
        float ab = __fadd_rn(__fmul_rn(__fsub_rn(B.z, A.z), __fdiv_rn(dx, den)),
                             __fmul_rn(__fsub_rn(B.w, A.w), __fdiv_rn(dy, den)));
        appr = ab < 0.0f;
    } else {
        appr = dot < 0.0f;
    }
    if (appr) {
        unsigned long long key = (((unsigned long long)__float_as_uint(d2)) << 16) |
                                 (unsigned)((i << 8) | j);
        kP = key < kP ? key : kP;
    }
}

// ---------------- dtype sniffer ----------------
__global__ void sniff_kernel(const unsigned short* st, int* ws) {
    __shared__ int ev;
    if (threadIdx.x == 0) ev = 0;
    __syncthreads();
    unsigned short u = st[threadIdx.x];
    int e = (u >> 7) & 0xFF;
    if (e >= 0x85) atomicOr(&ev, 1);
    __syncthreads();
    if (threadIdx.x == 0) ws[0] = ev ? 0 : 1;   // 1 = bf16, 0 = fp32
}

// ---------------- output row 0 = initial state (bit copy) ----------------
__global__ void row0_kernel(const void* in, void* out, const int* ws) {
    int idx = blockIdx.x * blockDim.x + threadIdx.x;
    if (ws[0]) ((unsigned short*)out)[idx] = ((const unsigned short*)in)[idx];
    else       ((float*)out)[idx] = ((const float*)in)[idx];
}

// ------- redundant-producer, wave0-decision, persistent-candidate event loop -------
__global__ __launch_bounds__(1024, 1) void sim_kernel(
    const void* in_state, const void* in_rad,
    const void* inW1, const void* inB1, const void* inW2, const void* inB2,
    const void* inW3, const void* inB3, const void* in_dt, const int* in_nsteps,
    void* out, const int* ws) {
    __shared__ float4 ps0[NB];          // batch-0 sim (decision state)
    __shared__ float4 psb[NB];          // own-batch sim
    __shared__ float rad[NB];
    __shared__ float w1[HID * 2], b1s[HID], w2[HID * W2S], b2s[HID], w3s[HID], b3s[1];
    __shared__ float sc0[132], scb[132];      // [4..67] h1, [68..131] h2
    __shared__ unsigned long long redP[16], redW[16];
    __shared__ float redF[4];
    __shared__ unsigned cand[CAND_MAX];
    __shared__ int candN;
    __shared__ int dI[4];
    __shared__ float dF[4];
    __shared__ int candF;
    __shared__ int rebF;               // rebuild flag for the NEXT step

    int tid = threadIdx.x;
    int b = blockIdx.x;
    int bf = ws[0];

    if (tid < NB) {
        int base0 = tid * 4;
        float4 P;
        P.x = rdin(in_state, base0 + 0, bf);
        P.y = rdin(in_state, base0 + 1, bf);
        P.z = rdin(in_state, base0 + 2, bf);
        P.w = rdin(in_state, base0 + 3, bf);
        ps0[tid] = P;
        int baseb = (b * NB + tid) * 4;
        float4 Q;
        Q.x = rdin(in_state, baseb + 0, bf);
        Q.y = rdin(in_state, baseb + 1, bf);
        Q.z = rdin(in_state, baseb + 2, bf);
        Q.w = rdin(in_state, baseb + 3, bf);
        psb[tid] = Q;
        rad[tid] = rdin(in_rad, tid, bf);
        float m2 = P.z * P.z + P.w * P.w;
        #pragma unroll
        for (int off = 32; off; off >>= 1) m2 = fmaxf(m2, __shfl_down(m2, off));
        if ((tid & 63) == 0) redF[tid >> 6] = m2;
    }
    load_weights(w1, b1s, w2, b2s, w3s, b3s, inW1, inB1, inW2, inB2, inW3, inB3, bf, tid, 1024);
    if (tid == 0) { candN = 0; candF = 0; rebF = 1; }

    float dtv = rdin(in_dt, 0, bf);
    int NS = in_nsteps[0]; if (NS > MAXSTEPS) NS = MAXSTEPS; if (NS < 0) NS = 0;

    // static tile assignment (one 6x6 tile per thread, tids 0..945)
    int myI0 = -1, myJ0 = 0;
    if (tid < NTILES) {
        int rem = tid, r = 0;
        while (rem >= NT - r) { rem -= NT - r; r++; }
        myI0 = r * 6; myJ0 = (r + rem) * 6;
    }
    __syncthreads();
    float rsum = __fadd_rn(rad[0], rad[0]);        // radii uniform

    // candidate list capture radius: covers CMARGIN total gap shrink (constant)
    float theta = __fadd_rn(__fadd_rn(rsum, 0.05f), CMARGIN);
    float th2 = __fmul_rn(theta, theta);

    int nc = 0;
    bool candOvf = false;
    // wave-0 persistent budget state: used = consumed shrink bound since rebuild,
    // vcap = monotone upper bound on sim-0 max speed since rebuild
    float used = 1e30f, vcap = 0.0f;

    for (int s = 0; s < NS; s++) {
        int rebuild = rebF;
        float t_s = __fmul_rn((float)s, dtv);
        float t_e = __fadd_rn(t_s, dtv);
        float t_c = t_s;
        if (tid < 64) {
            if (rebuild) {
                vcap = sqrtf(fmaxf(fmaxf(redF[0], redF[1]), fmaxf(redF[2], redF[3])));
                used = 0.0f;
            }
            // pre-charge this step's worst-case motion (bit-identical to rebF check)
            used = __fadd_rn(used, __fmul_rn(__fmul_rn(2.0f, dtv), vcap));
            if (tid == 0 && rebuild) candF = 0;
        }

        for (int e = 0; e < MAXEV; e++) {
            // ---------- detect phase (all 1024 threads) ----------
            unsigned long long kP = ~0ull, kW = ~0ull;
            bool fullscan = (e == 0) ? (rebuild != 0) : (candF != 0);
            bool doAppend = (e == 0) && rebuild;
            if (fullscan) {
                if (myI0 >= 0) {
                    float4 Pi[6], Pj[6];
                    #pragma unroll
                    for (int a = 0; a < 6; a++) {
                        int ii = myI0 + a; ii = ii < NB ? ii : NB - 1;
                        int jj = myJ0 + a; jj = jj < NB ? jj : NB - 1;
                        Pi[a] = ps0[ii]; Pj[a] = ps0[jj];
                    }
                    #pragma unroll
                    for (int a = 0; a < 6; a++) {
                        int i = myI0 + a;
                        #pragma unroll
                        for (int bb = 0; bb < 6; bb++) {
                            int j = myJ0 + bb;
                            bool ok = (i < NB) && (j < NB) && (j > i);
                            float dx = __fsub_rn(Pj[bb].x, Pi[a].x);
                            float dy = __fsub_rn(Pj[bb].y, Pi[a].y);
                            float d2 = __fadd_rn(__fmul_rn(dx, dx), __fmul_rn(dy, dy));
                            float p1 = __fmul_rn(__fsub_rn(Pj[bb].z, Pi[a].z), dx);
                            float p2 = __fmul_rn(__fsub_rn(Pj[bb].w, Pi[a].w), dy);
                            float dot = __fadd_rn(p1, p2);
                            float mag = __fadd_rn(fabsf(p1), fabsf(p2));
                            bool appr;
                            if (fabsf(dot) < __fmul_rn(1e-5f, mag)) {
                                float dist = __fsqrt_rn(d2);
                                float den = __fadd_rn(dist, 1e-8f);
                                float ab = __fadd_rn(
                                    __fmul_rn(__fsub_rn(Pj[bb].z, Pi[a].z), __fdiv_rn(dx, den)),
                                    __fmul_rn(__fsub_rn(Pj[bb].w, Pi[a].w), __fdiv_rn(dy, den)));
                                appr = ab < 0.0f;
                            } else {
                                appr = dot < 0.0f;
                            }
                            if (ok && appr) {
                                unsigned long long key =
                                    (((unsigned long long)__float_as_uint(d2)) << 16) |
                                    (unsigned)((i << 8) | j);
                                kP = key < kP ? key : kP;
                            }
                            if (doAppend && ok && d2 < th2) {
                                int x = atomicAdd(&candN, 1);
                                if (x < CAND_MAX) cand[x] = (unsigned)((i << 8) | j);
                            }
                        }
                    }
                }
            } else {
                for (int c = tid; c < nc; c += 1024) {
                    unsigned id = cand[c];
                    pair_min(ps0, (int)(id >> 8), (int)(id & 255u), kP);
                }
            }
            {   // wall candidate: exactly one per thread (tid = ball*4+w)
                int ball = tid >> 2, w = tid & 3;
                float4 P = ps0[ball]; float r = rad[ball];
                float g; bool valid;
                if (w == 0)      { g = __fsub_rn(P.x, r); valid = P.z < 0.0f; }
                else if (w == 1) { g = __fsub_rn(__fsub_rn(10.0f, P.x), r); valid = P.z > 0.0f; }
                else if (w == 2) { g = __fsub_rn(P.y, r); valid = P.w < 0.0f; }
                else             { g = __fsub_rn(__fsub_rn(10.0f, P.y), r); valid = P.w > 0.0f; }
                if (valid) {
                    unsigned gb = __float_as_uint(g);
                    unsigned m = (unsigned)(((int)gb) >> 31) | 0x80000000u;
                    unsigned sb = gb ^ m;
                    unsigned long long key = (((unsigned long long)sb) << 16) | (unsigned)tid;
                    kW = key < kW ? key : kW;
                }
            }
            #pragma unroll
            for (int off = 32; off; off >>= 1) {
                unsigned long long o1 = shfl_down_u64(kP, off);
                unsigned long long o2 = shfl_down_u64(kW, off);
                kP = o1 < kP ? o1 : kP;
                kW = o2 < kW ? o2 : kW;
            }
            if ((tid & 63) == 0) { redP[tid >> 6] = kP; redW[tid >> 6] = kW; }
            __syncthreads();                                     // B1

            if (e == 0 && rebuild) {
                int ct = candN;
                candOvf = ct > CAND_MAX;
                nc = candOvf ? CAND_MAX : ct;
            }

            // ---------- decision: wave 0 only; sim0 geometry kept in registers ----------
            float g_nx = 0, g_ny = 0, g_dist = 0, g_app = 0;
            float4 gA, gB;
            if (tid < 64) {
                unsigned long long mP = redP[0], mW = redW[0];
                #pragma unroll
                for (int q = 1; q < 16; q++) {
                    mP = redP[q] < mP ? redP[q] : mP;
                    mW = redW[q] < mW ? redW[q] : mW;
                }
                float gball = 1e30f; int pi = 0, pj = 1;
                if (mP != ~0ull) {
                    unsigned id = (unsigned)(mP & 0xFFFFull);
                    pi = id >> 8; pj = id & 255u;
                    float d2 = __uint_as_float((unsigned)(mP >> 16));
                    gball = __fsub_rn(__fsqrt_rn(d2), rsum);
                }
                float gwall = 1e30f; int wb = 0, ww = 0;
                if (mW != ~0ull) {
                    unsigned id = (unsigned)(mW & 0xFFFFull);
                    wb = id >> 2; ww = id & 3u;
                    unsigned sb = (unsigned)(mW >> 16);
                    unsigned gb = (sb & 0x80000000u) ? (sb ^ 0x80000000u) : ~sb;
                    gwall = __uint_as_float(gb);
                }
                bool is_ball = gball <= gwall;
                float gap = is_ball ? gball : gwall;
                int code_ = 0; float dteB_ = 0.0f, tcn_ = t_c;
                if (!(gap > 0.05f)) {
                    float app;
                    if (is_ball) {
                        float4 A = ps0[pi], B = ps0[pj];
                        float dx = __fsub_rn(B.x, A.x), dy = __fsub_rn(B.y, A.y);
                        float nrm = __fsqrt_rn(__fadd_rn(__fmul_rn(dx, dx), __fmul_rn(dy, dy)));
                        float dvx = __fsub_rn(B.z, A.z), dvy = __fsub_rn(B.w, A.w);
                        app = -__fadd_rn(__fdiv_rn(__fmul_rn(dvx, dx), nrm),
                                         __fdiv_rn(__fmul_rn(dvy, dy), nrm));
                    } else {
                        float4 Wb = ps0[wb];
                        app = fabsf(fmaxf(Wb.z, Wb.w));
                    }
                    float t_ev = __fadd_rn(t_c, __fdiv_rn(gap, fmaxf(app, 1e-6f)));
                    if (gap <= 0.0f) {
                        code_ = is_ball ? 1 : 3;
                    } else if (app > 1e-6f && t_ev < t_e) {
                        code_ = is_ball ? 2 : 4;
                        dteB_ = (t_ev > __fadd_rn(t_c, 1e-10f)) ? __fsub_rn(t_ev, t_c) : 0.0f;
                        tcn_ = t_ev;
                    }
                }
                int ei_ = is_ball ? pi : wb;
                int ej_ = is_ball ? pj : ww;
                if (tid == 0) {
                    dI[0] = code_; dI[1] = ei_; dI[2] = ej_;
                    dF[0] = dteB_; dF[1] = tcn_;
                }
                if (code_ != 0 && code_ <= 2) {
                    // sim0 geometry kept in registers
                    float4 A = ps0[ei_], B = ps0[ej_];
                    if (code_ == 2) {
                        A.x = __fadd_rn(A.x, __fmul_rn(A.z, dteB_));
                        A.y = __fadd_rn(A.y, __fmul_rn(A.w, dteB_));
                        B.x = __fadd_rn(B.x, __fmul_rn(B.z, dteB_));
                        B.y = __fadd_rn(B.y, __fmul_rn(B.w, dteB_));
                    }
                    gA = A; gB = B;
                    float dx = __fsub_rn(B.x, A.x), dy = __fsub_rn(B.y, A.y);
                    float nrm = __fsqrt_rn(__fadd_rn(__fmul_rn(dx, dx), __fmul_rn(dy, dy)));
                    float dist = fmaxf(nrm, 1e-8f);
                    g_nx = __fdiv_rn(dx, dist); g_ny = __fdiv_rn(dy, dist);
                    g_dist = dist;
                    float dvx = __fsub_rn(B.z, A.z), dvy = __fsub_rn(B.w, A.w);
                    g_app = __fadd_rn(__fmul_rn(dvx, g_nx), __fmul_rn(dvy, g_ny));
                }
            }
            __syncthreads();                                     // B1b (publish)

            int code = dI[0];
            if (code == 0) break;
            int ei = dI[1], ejw = dI[2];
            float dteB = dF[0];
            t_c = dF[1];
            bool integ = (code == 2) || (code == 4);

            // ---------- apply phase P2 (one barrier at end) ----------
            if (code <= 2) {
                if (tid < 64) {
                    // wave 0: sim0 MLP from registers, in-wave LDS round-trips
                    float a = __fadd_rn(__fadd_rn(__fmul_rn(g_dist, w1[2 * tid]),
                                                  __fmul_rn(g_app, w1[2 * tid + 1])), b1s[tid]);
                    sc0[4 + tid] = silu_f(a);
                    lds_fence();
                    float acc = 0.0f;
                    const float* row = &w2[tid * W2S];
                    #pragma unroll 8
                    for (int k = 0; k < HID; k++) acc = __fadd_rn(acc, __fmul_rn(sc0[4 + k], row[k]));
                    acc = __fadd_rn(acc, b2s[tid]);
                    sc0[68 + tid] = silu_f(acc);
                    lds_fence();
                    float acc3 = 0.0f;
                    #pragma unroll 8
                    for (int k = 0; k < HID; k++)
                        acc3 = __fadd_rn(acc3, __fmul_rn(sc0[68 + k], w3s[k]));
                    float impv = __fadd_rn(acc3, b3s[0]);
                    float ix = __fmul_rn(impv, g_nx), iy = __fmul_rn(impv, g_ny);
                    float nAz = __fadd_rn(gA.z, ix),  nAw = __fadd_rn(gA.w, iy);
                    float nBz = __fadd_rn(gB.z, -ix), nBw = __fadd_rn(gB.w, -iy);
                    if (tid == 0) {
                        float4 outA; outA.x = gA.x; outA.y = gA.y; outA.z = nAz; outA.w = nAw;
                        float4 outB; outB.x = gB.x; outB.y = gB.y; outB.z = nBz; outB.w = nBw;
                        ps0[ei] = outA; ps0[ejw] = outB;
                    }
                    float s1 = sqrtf(nAz * nAz + nAw * nAw);
                    float s2 = sqrtf(nBz * nBz + nBw * nBw);
                    float nv = fmaxf(s1, s2);
                    used = __fadd_rn(used, __fmul_rn(__fmul_rn(2.0f, dtv),
                                                     fmaxf(__fsub_rn(nv, vcap), 0.0f)));
                    vcap = fmaxf(vcap, nv);
                    int nf = (candOvf || (__fadd_rn(used, 1e-3f) > CMARGIN)) ? 1 : 0;
                    if (tid == 0) candF = nf;
                } else if (tid < 128) {
                    // wave 1: simb full apply (geometry + MLP), in-wave
                    int lane = tid - 64;
                    float4 A = psb[ei], B = psb[ejw];
                    if (integ) {
                        A.x = __fadd_rn(A.x, __fmul_rn(A.z, dteB));
                        A.y = __fadd_rn(A.y, __fmul_rn(A.w, dteB));
                        B.x = __fadd_rn(B.x, __fmul_rn(B.z, dteB));
                        B.y = __fadd_rn(B.y, __fmul_rn(B.w, dteB));
                    }
                    float dx = __fsub_rn(B.x, A.x), dy = __fsub_rn(B.y, A.y);
                    float nrm = __fsqrt_rn(__fadd_rn(__fmul_rn(dx, dx), __fmul_rn(dy, dy)));
                    float dist = fmaxf(nrm, 1e-8f);
                    float nx = __fdiv_rn(dx, dist), ny = __fdiv_rn(dy, dist);
                    float dvx = __fsub_rn(B.z, A.z), dvy = __fsub_rn(B.w, A.w);
                    float app2 = __fadd_rn(__fmul_rn(dvx, nx), __fmul_rn(dvy, ny));
                    float a = __fadd_rn(__fadd_rn(__fmul_rn(dist, w1[2 * lane]),
                                                  __fmul_rn(app2, w1[2 * lane + 1])), b1s[lane]);
                    scb[4 + lane] = silu_f(a);
                    lds_fence();
                    float acc = 0.0f;
                    const float* row = &w2[lane * W2S];
                    #pragma unroll 8
                    for (int k = 0; k < HID; k++) acc = __fadd_rn(acc, __fmul_rn(scb[4 + k], row[k]));
                    acc = __fadd_rn(acc, b2s[lane]);
                    scb[68 + lane] = silu_f(acc);
                    lds_fence();
                    float acc3 = 0.0f;
                    #pragma unroll 8
                    for (int k = 0; k < HID; k++)
                        acc3 = __fadd_rn(acc3, __fmul_rn(scb[68 + k], w3s[k]));
                    float impv = __fadd_rn(acc3, b3s[0]);
                    if (lane == 0) {
                        float ix = __fmul_rn(impv, nx), iy = __fmul_rn(impv, ny);
                        float4 outA; outA.x = A.x; outA.y = A.y;
                        outA.z = __fadd_rn(A.z, ix);  outA.w = __fadd_rn(A.w, iy);
                        float4 outB; outB.x = B.x; outB.y = B.y;
                        outB.z = __fadd_rn(B.z, -ix); outB.w = __fadd_rn(B.w, -iy);
                        psb[ei] = outA; psb[ejw] = outB;
                    }
                } else if (tid < 384) {
                    int t = tid - 128;
                    if (integ && t != ei && t != ejw) {
                        float4 P = ps0[t];
                        P.x = __fadd_rn(P.x, __fmul_rn(P.z, dteB));
                        P.y = __fadd_rn(P.y, __fmul_rn(P.w, dteB));
                        ps0[t] = P;
                    }
                } else if (tid < 640) {
                    int t = tid - 384;
                    if (integ && t != ei && t != ejw) {
                        float4 Q = psb[t];
                        Q.x = __fadd_rn(Q.x, __fmul_rn(Q.z, dteB));
                        Q.y = __fadd_rn(Q.y, __fmul_rn(Q.w, dteB));
                        psb[t] = Q;
                    }
                }
                __syncthreads();                                 // P2 end
            } else {
                // ---------- wall event ----------
                const float wnx[4] = {1.f, -1.f, 0.f, 0.f};
                const float wny[4] = {0.f, 0.f, 1.f, -1.f};
                const float wpv[4] = {0.f, -10.f, 0.f, -10.f};
                int w = ejw;
                if (tid < 64) {
                    float4 P = ps0[ei];
                    if (integ) {
                        P.x = __fadd_rn(P.x, __fmul_rn(P.z, dteB));
                        P.y = __fadd_rn(P.y, __fmul_rn(P.w, dteB));
                    }
                    float vn = __fadd_rn(__fmul_rn(P.z, wnx[w]), __fmul_rn(P.w, wny[w]));
                    float t2 = __fmul_rn(2.0f, vn);
                    float nvx = __fsub_rn(P.z, __fmul_rn(t2, wnx[w]));
                    float nvy = __fsub_rn(P.w, __fmul_rn(t2, wny[w]));
                    float pn = __fadd_rn(__fmul_rn(P.x, wnx[w]), __fmul_rn(P.y, wny[w]));
                    float pen = fmaxf(__fsub_rn(__fadd_rn(wpv[w], rad[ei]), pn), 0.0f);
                    float4 nP;
                    nP.x = __fadd_rn(P.x, __fmul_rn(pen, wnx[w]));
                    nP.y = __fadd_rn(P.y, __fmul_rn(pen, wny[w]));
                    nP.z = nvx; nP.w = nvy;
                    used = __fadd_rn(used, pen);
                    int nf = (candOvf || (__fadd_rn(used, 1e-3f) > CMARGIN)) ? 1 : 0;
                    if (tid == 0) { ps0[ei] = nP; candF = nf; }
                } else if (tid < 128) {
                    if (tid == 64) {
                        float4 P = psb[ei];
                        if (integ) {
                            P.x = __fadd_rn(P.x, __fmul_rn(P.z, dteB));
                            P.y = __fadd_rn(P.y, __fmul_rn(P.w, dteB));
                        }
                        float vn = __fadd_rn(__fmul_rn(P.z, wnx[w]), __fmul_rn(P.w, wny[w]));
                        float t2 = __fmul_rn(2.0f, vn);
                        float nvx = __fsub_rn(P.z, __fmul_rn(t2, wnx[w]));
                        float nvy = __fsub_rn(P.w, __fmul_rn(t2, wny[w]));
                        float pn = __fadd_rn(__fmul_rn(P.x, wnx[w]), __fmul_rn(P.y, wny[w]));
                        float pen = fmaxf(__fsub_rn(__fadd_rn(wpv[w], rad[ei]), pn), 0.0f);
                        float4 nP;
                        nP.x = __fadd_rn(P.x, __fmul_rn(pen, wnx[w]));
                        nP.y = __fadd_rn(P.y, __fmul_rn(pen, wny[w]));
                        nP.z = nvx; nP.w = nvy;
                        psb[ei] = nP;
                    }
                } else if (tid < 384) {
                    int t = tid - 128;
                    if (integ && t != ei) {
                        float4 P = ps0[t];
                        P.x = __fadd_rn(P.x, __fmul_rn(P.z, dteB));
                        P.y = __fadd_rn(P.y, __fmul_rn(P.w, dteB));
                        ps0[t] = P;
                    }
                } else if (tid < 640) {
                    int t = tid - 384;
                    if (integ && t != ei) {
                        float4 Q = psb[t];
                        Q.x = __fadd_rn(Q.x, __fmul_rn(Q.z, dteB));
                        Q.y = __fadd_rn(Q.y, __fmul_rn(Q.w, dteB));
                        psb[t] = Q;
                    }
                }
                __syncthreads();                                 // P2 end
            }
        }

        // ---------- step end: final integrate + vmax + store (fused) ----------
        float fd = (t_e > __fadd_rn(t_c, 1e-10f)) ? __fsub_rn(t_e, t_c) : 0.0f;
        if (tid < NB) {
            float4 P = ps0[tid];
            P.x = __fadd_rn(P.x, __fmul_rn(P.z, fd));
            P.y = __fadd_rn(P.y, __fmul_rn(P.w, fd));
            ps0[tid] = P;
            float m2 = P.z * P.z + P.w * P.w;
            #pragma unroll
            for (int off = 32; off; off >>= 1) m2 = fmaxf(m2, __shfl_down(m2, off));
            if ((tid & 63) == 0) redF[tid >> 6] = m2;
            if (tid == 0) {
                candN = 0;
                // schedule rebuild iff next step's pre-charge would blow the budget
                // (bit-identical arithmetic to the step-start pre-charge)
                float usedNext = __fadd_rn(used, __fmul_rn(__fmul_rn(2.0f, dtv), vcap));
                rebF = (candOvf || (__fadd_rn(usedNext, 1e-3f) > CMARGIN)) ? 1 : 0;
            }
        } else if (tid < 2 * NB) {
            int t = tid - NB;
            float4 Q = psb[t];
            Q.x = __fadd_rn(Q.x, __fmul_rn(Q.z, fd));
            Q.y = __fadd_rn(Q.y, __fmul_rn(Q.w, fd));
            psb[t] = Q;
            long long base = ((long long)(s + 1) * NBATCH + b) * (NB * 4);
            if (bf) {
                ushort4 v;
                v.x = f2bf(Q.x); v.y = f2bf(Q.y); v.z = f2bf(Q.z); v.w = f2bf(Q.w);
                ((ushort4*)((unsigned short*)out + base))[t] = v;
            } else {
                ((float4*)((float*)out + base))[t] = Q;
            }
        }
        __syncthreads();
    }
}

extern "C" void kernel_launch(void* const* d_in, const int* in_sizes, int n_in,
                              void* d_out, int out_size, void* d_ws, size_t ws_size,
                              hipStream_t stream) {
    // inputs: 0 state, 1 radii, 2 W1, 3 b1, 4 W2, 5 b2, 6 W3, 7 b3, 8 dt, 9 n_steps
    int* ws = (int*)d_ws;
    sniff_kernel<<<1, 256, 0, stream>>>((const unsigned short*)d_in[0], ws);
    row0_kernel<<<(NBATCH * NB * 4) / 256, 256, 0, stream>>>(d_in[0], d_out, ws);
    sim_kernel<<<NBATCH, 1024, 0, stream>>>(
        d_in[0], d_in[1], d_in[2], d_in[3], d_in[4], d_in[5], d_in[6], d_in[7],
        d_in[8], (const int*)d_in[9], d_out, ws);
}